// Round 1
// baseline (998.175 us; speedup 1.0000x reference)
//
#include <hip/hip_runtime.h>
#include <hip/hip_bf16.h>

#define DIM_  768
#define NH    12
#define HD    64
#define BB    2
#define NN    2048
#define MM    (BB*NN)      // 4096
#define QKVD  (3*DIM_)     // 2304

__device__ __forceinline__ float warp16_max(float v) {
    #pragma unroll
    for (int off = 1; off < 16; off <<= 1) v = fmaxf(v, __shfl_xor(v, off));
    return v;
}
__device__ __forceinline__ float warp16_sum(float v) {
    #pragma unroll
    for (int off = 1; off < 16; off <<= 1) v += __shfl_xor(v, off);
    return v;
}

// C[m,n] = sum_k A[m,k] * W[n,k] (+ bias[n]); A:(Md,K) W:(Nd,K) row-major.
// All dims multiples of 64 (K multiple of 16) -- no bounds checks.
__global__ __launch_bounds__(256)
void gemm_nt(const float* __restrict__ A, const float* __restrict__ W,
             const float* __restrict__ bias, float* __restrict__ C,
             int Md, int Nd, int K)
{
    __shared__ float As[64][17];
    __shared__ float Ws[64][17];
    const int tid = threadIdx.x;
    const int tx = tid & 15, ty = tid >> 4;
    const int n0 = blockIdx.x * 64;
    const int m0 = blockIdx.y * 64;

    const int lr = tid >> 2;         // 0..63
    const int lc = (tid & 3) * 4;    // 0,4,8,12

    float acc[4][4] = {};
    for (int k0 = 0; k0 < K; k0 += 16) {
        float4 av = *(const float4*)(A + (size_t)(m0 + lr) * K + k0 + lc);
        float4 wv = *(const float4*)(W + (size_t)(n0 + lr) * K + k0 + lc);
        As[lr][lc+0]=av.x; As[lr][lc+1]=av.y; As[lr][lc+2]=av.z; As[lr][lc+3]=av.w;
        Ws[lr][lc+0]=wv.x; Ws[lr][lc+1]=wv.y; Ws[lr][lc+2]=wv.z; Ws[lr][lc+3]=wv.w;
        __syncthreads();
        #pragma unroll
        for (int kk = 0; kk < 16; ++kk) {
            float a[4], b[4];
            #pragma unroll
            for (int i = 0; i < 4; ++i) a[i] = As[ty*4+i][kk];
            #pragma unroll
            for (int j = 0; j < 4; ++j) b[j] = Ws[tx*4+j][kk];
            #pragma unroll
            for (int i = 0; i < 4; ++i)
                #pragma unroll
                for (int j = 0; j < 4; ++j)
                    acc[i][j] = fmaf(a[i], b[j], acc[i][j]);
        }
        __syncthreads();
    }
    #pragma unroll
    for (int i = 0; i < 4; ++i) {
        const int m = m0 + ty*4 + i;
        #pragma unroll
        for (int j = 0; j < 4; ++j) {
            const int n = n0 + tx*4 + j;
            float v = acc[i][j];
            if (bias) v += bias[n];
            C[(size_t)m * Nd + n] = v;
        }
    }
}

// Flash-style attention over qkv buffer laid out (B, N, 3, NH, HD).
// One block = 64 queries of one (b,h). Online softmax, masked keys get p=0.
__global__ __launch_bounds__(256)
void attn(const float* __restrict__ qkv, const int* __restrict__ pmask,
          float* __restrict__ xout)
{
    const int ntq = NN / 64;
    const int qt = blockIdx.x % ntq;
    const int bh = blockIdx.x / ntq;
    const int h  = bh % NH, b = bh / NH;

    __shared__ float Qs[64][HD+1];
    __shared__ float Ks[64][HD+1];
    __shared__ float Vs[64][HD];
    __shared__ float Ps[64][65];
    __shared__ int   msk[64];

    const int tid = threadIdx.x;
    const int tx = tid & 15, ty = tid >> 4;
    const int lr = tid >> 2;              // row this thread loads
    const int cbase = (tid & 3) * 16;     // 16-float chunk within the row

    const size_t qbase = (size_t)b * NN * QKVD;

    { // load Q tile (s=0)
        const float* src = qkv + qbase + (size_t)(qt*64 + lr) * QKVD + h*HD;
        #pragma unroll
        for (int c = 0; c < 4; ++c) {
            const int col = cbase + c*4;
            float4 v = *(const float4*)(src + col);
            Qs[lr][col+0]=v.x; Qs[lr][col+1]=v.y; Qs[lr][col+2]=v.z; Qs[lr][col+3]=v.w;
        }
    }

    float mrow[4], lrow[4], accx[4][4] = {};
    #pragma unroll
    for (int i = 0; i < 4; ++i) { mrow[i] = -1e30f; lrow[i] = 0.f; }

    constexpr float SCALE = 0.125f;  // 64^-0.5

    for (int kt = 0; kt < NN/64; ++kt) {
        { // load K (s=1), V (s=2) tiles + mask
            const float* ksrc = qkv + qbase + (size_t)(kt*64 + lr) * QKVD + DIM_   + h*HD;
            const float* vsrc = qkv + qbase + (size_t)(kt*64 + lr) * QKVD + 2*DIM_ + h*HD;
            #pragma unroll
            for (int c = 0; c < 4; ++c) {
                const int col = cbase + c*4;
                float4 kv = *(const float4*)(ksrc + col);
                Ks[lr][col+0]=kv.x; Ks[lr][col+1]=kv.y; Ks[lr][col+2]=kv.z; Ks[lr][col+3]=kv.w;
                *(float4*)&Vs[lr][col] = *(const float4*)(vsrc + col);
            }
            if (tid < 64) msk[tid] = pmask[b*NN + kt*64 + tid];
        }
        __syncthreads();

        // S = (Q K^T) * SCALE
        float s[4][4] = {};
        #pragma unroll
        for (int kk = 0; kk < HD; ++kk) {
            float a[4], bb[4];
            #pragma unroll
            for (int i = 0; i < 4; ++i) a[i] = Qs[ty*4+i][kk];
            #pragma unroll
            for (int j = 0; j < 4; ++j) bb[j] = Ks[tx*4+j][kk];
            #pragma unroll
            for (int i = 0; i < 4; ++i)
                #pragma unroll
                for (int j = 0; j < 4; ++j)
                    s[i][j] = fmaf(a[i], bb[j], s[i][j]);
        }
        bool mj[4];
        #pragma unroll
        for (int j = 0; j < 4; ++j) mj[j] = msk[tx*4+j] > 0;

        #pragma unroll
        for (int i = 0; i < 4; ++i) {
            float rv = -1e30f;
            #pragma unroll
            for (int j = 0; j < 4; ++j) {
                s[i][j] *= SCALE;
                if (!mj[j]) rv = fmaxf(rv, s[i][j]);
            }
            const float rm = warp16_max(rv);
            const float mnew = fmaxf(mrow[i], rm);
            const float corr = __expf(mrow[i] - mnew);   // exp(0)=1 when both -1e30: acc/l are 0, safe
            mrow[i] = mnew;
            float p[4], psum = 0.f;
            #pragma unroll
            for (int j = 0; j < 4; ++j) {
                p[j] = mj[j] ? 0.f : __expf(s[i][j] - mnew);
                psum += p[j];
            }
            psum = warp16_sum(psum);
            lrow[i] = lrow[i] * corr + psum;
            #pragma unroll
            for (int j = 0; j < 4; ++j) accx[i][j] *= corr;
            #pragma unroll
            for (int j = 0; j < 4; ++j) Ps[ty*4+i][tx*4+j] = p[j];
        }
        __syncthreads();

        // accx += P @ V
        #pragma unroll 8
        for (int c = 0; c < 64; ++c) {
            float pa[4], vb[4];
            #pragma unroll
            for (int i = 0; i < 4; ++i) pa[i] = Ps[ty*4+i][c];
            #pragma unroll
            for (int j = 0; j < 4; ++j) vb[j] = Vs[c][tx*4+j];
            #pragma unroll
            for (int i = 0; i < 4; ++i)
                #pragma unroll
                for (int j = 0; j < 4; ++j)
                    accx[i][j] = fmaf(pa[i], vb[j], accx[i][j]);
        }
        __syncthreads();
    }

    // write x in (B, N, NH*HD) layout
    #pragma unroll
    for (int i = 0; i < 4; ++i) {
        const float inv = 1.0f / lrow[i];
        const int r = ty*4 + i;
        #pragma unroll
        for (int j = 0; j < 4; ++j) {
            const int d = tx*4 + j;
            xout[((size_t)(b*NN + qt*64 + r)) * DIM_ + h*HD + d] = accx[i][j] * inv;
        }
    }
}

extern "C" void kernel_launch(void* const* d_in, const int* in_sizes, int n_in,
                              void* d_out, int out_size, void* d_ws, size_t ws_size,
                              hipStream_t stream)
{
    const float* x     = (const float*)d_in[0];
    const int*   pmask = (const int*)d_in[1];
    const float* wqkv  = (const float*)d_in[2];
    const float* wfc   = (const float*)d_in[3];
    const float* bfc   = (const float*)d_in[4];
    float* out = (float*)d_out;

    float* qkv  = (float*)d_ws;                       // MM*QKVD fp32 = 36 MB
    float* xatt = qkv + (size_t)MM * QKVD;            // MM*DIM_  fp32 = 12 MB

    gemm_nt<<<dim3(QKVD/64, MM/64), 256, 0, stream>>>(x, wqkv, nullptr, qkv, MM, QKVD, DIM_);
    attn<<<dim3(BB*NH*(NN/64)), 256, 0, stream>>>(qkv, pmask, xatt);
    gemm_nt<<<dim3(DIM_/64, MM/64), 256, 0, stream>>>(xatt, wfc, bfc, out, MM, DIM_, DIM_);
}

// Round 2
// 238.608 us; speedup vs baseline: 4.1833x; 4.1833x over previous
//
#include <hip/hip_runtime.h>
#include <hip/hip_bf16.h>

#define DIM_  768
#define NH    12
#define HD    64
#define BB    2
#define NN    2048
#define MM    (BB*NN)      // 4096
#define QKVD  (3*DIM_)     // 2304

typedef __attribute__((ext_vector_type(8))) short          bf16x8;
typedef __attribute__((ext_vector_type(8))) unsigned short u16x8;
typedef __attribute__((ext_vector_type(4))) float          f32x4;

__device__ __forceinline__ unsigned short f2bf(float f) {
    __hip_bfloat16 h = __float2bfloat16(f);
    unsigned short u; __builtin_memcpy(&u, &h, 2); return u;
}

// async global->LDS, 16B per lane. Dest = wave-uniform base + lane*16 (HW).
__device__ __forceinline__ void gload16(const void* g, void* lds) {
    __builtin_amdgcn_global_load_lds(
        (const __attribute__((address_space(1))) void*)g,
        (__attribute__((address_space(3))) void*)lds, 16, 0, 0);
}

__global__ __launch_bounds__(256)
void cast_f32_bf16(const float* __restrict__ in, unsigned short* __restrict__ out, int n) {
    int i = (blockIdx.x * blockDim.x + threadIdx.x) * 4;
    if (i < n) {
        float4 v = *(const float4*)(in + i);
        ushort4 o; o.x = f2bf(v.x); o.y = f2bf(v.y); o.z = f2bf(v.z); o.w = f2bf(v.w);
        *(ushort4*)(out + i) = o;
    }
}

// C[m,n] = sum_k A[m,k]*W[n,k] (+bias). A:(Md,K) W:(Nd,K) bf16 row-major.
// 128x128 tile, 4 waves, BK=32, global_load_lds staging (m97 structure).
template<int WRITE_BF16>
__global__ __launch_bounds__(256)
void gemm_mfma(const unsigned short* __restrict__ A, const unsigned short* __restrict__ W,
               const float* __restrict__ bias, void* __restrict__ Cout,
               int Md, int Nd, int K)
{
    __shared__ unsigned short As[128 * 32];   // linear, 64B rows
    __shared__ unsigned short Bs[128 * 32];
    const int tid  = threadIdx.x;
    const int lane = tid & 63, wave = tid >> 6;
    const int wr = wave >> 1, wc = wave & 1;       // wave -> 64x64 quadrant
    const int n0 = blockIdx.x * 128, m0 = blockIdx.y * 128;

    f32x4 acc[4][4];
    #pragma unroll
    for (int i = 0; i < 4; ++i)
        #pragma unroll
        for (int j = 0; j < 4; ++j) acc[i][j] = (f32x4){0.f, 0.f, 0.f, 0.f};

    const int ldrow = lane >> 2;   // 16 rows per 1KB chunk
    const int ldg   = lane & 3;    // 16B granule within 64B row

    for (int k0 = 0; k0 < K; k0 += 32) {
        #pragma unroll
        for (int rd = 0; rd < 2; ++rd) {
            const int chunk = rd * 4 + wave;            // 0..7 (wave-uniform)
            const int row   = chunk * 16 + ldrow;       // 0..127
            gload16(A + (size_t)(m0 + row) * K + k0 + ldg * 8, (char*)As + chunk * 1024);
            gload16(W + (size_t)(n0 + row) * K + k0 + ldg * 8, (char*)Bs + chunk * 1024);
        }
        __syncthreads();   // compiler drains vmcnt before barrier

        bf16x8 af[4], bf_[4];
        #pragma unroll
        for (int i = 0; i < 4; ++i)
            af[i] = *(const bf16x8*)((const char*)As + (wr*64 + i*16 + (lane & 15)) * 64 + (lane >> 4) * 16);
        #pragma unroll
        for (int j = 0; j < 4; ++j)
            bf_[j] = *(const bf16x8*)((const char*)Bs + (wc*64 + j*16 + (lane & 15)) * 64 + (lane >> 4) * 16);
        #pragma unroll
        for (int i = 0; i < 4; ++i)
            #pragma unroll
            for (int j = 0; j < 4; ++j)
                acc[i][j] = __builtin_amdgcn_mfma_f32_16x16x32_bf16(af[i], bf_[j], acc[i][j], 0, 0, 0);
        __syncthreads();
    }

    const int r0 = (lane >> 4) * 4, cl = lane & 15;
    #pragma unroll
    for (int i = 0; i < 4; ++i) {
        #pragma unroll
        for (int j = 0; j < 4; ++j) {
            const int n = n0 + wc * 64 + j * 16 + cl;
            const float bv = bias ? bias[n] : 0.f;
            #pragma unroll
            for (int r = 0; r < 4; ++r) {
                const int m = m0 + wr * 64 + i * 16 + r0 + r;
                const float v = acc[i][j][r] + bv;
                if (WRITE_BF16) ((unsigned short*)Cout)[(size_t)m * Nd + n] = f2bf(v);
                else            ((float*)Cout)[(size_t)m * Nd + n] = v;
            }
        }
    }
}

// Flash attention, bf16 MFMA. Block = (b, h, 64-query tile); 4 waves x 16 q-rows.
__global__ __launch_bounds__(256)
void attn_mfma(const unsigned short* __restrict__ qkv, const int* __restrict__ pmask,
               unsigned short* __restrict__ xout)
{
    __shared__ unsigned short Qs[64 * 64];      // [row][64] bf16, XOR-granule swizzled
    __shared__ unsigned short Ks[64 * 64];
    __shared__ unsigned short Vt[64 * 64];      // V^T: [d][kv], swizzled
    __shared__ unsigned short Ps[4][16 * 72];   // per-wave P [16][72] bf16
    __shared__ float maskf[64];

    const int tid = threadIdx.x, lane = tid & 63, wave = tid >> 6;
    const int ntq = NN / 64;
    const int qt = blockIdx.x % ntq;
    const int bh = blockIdx.x / ntq;
    const int h = bh % NH, b = bh / NH;
    const size_t base = (size_t)b * NN * QKVD;
    const int hoff = h * HD;
    constexpr float SCALE = 0.125f;

    const int sr = lane >> 3;   // row within 1KB chunk (8 rows of 128B)
    const int sg = lane & 7;    // dest granule

    // ---- stage Q once (swizzled source -> linear dest) ----
    #pragma unroll
    for (int rd = 0; rd < 2; ++rd) {
        const int chunk = rd * 4 + wave;
        const int row = chunk * 8 + sr;
        const int gsrc = (sg ^ (row & 7)) * 8;    // element offset
        gload16(qkv + base + (size_t)(qt * 64 + row) * QKVD + hoff + gsrc,
                (char*)Qs + chunk * 1024);
    }
    __syncthreads();

    // hoist Q fragments (q-row = wave*16 + lane%16)
    bf16x8 qf[2];
    {
        const int qrow = wave * 16 + (lane & 15);
        #pragma unroll
        for (int ks = 0; ks < 2; ++ks) {
            const int g = ((lane >> 4) + ks * 4) ^ (lane & 7);
            qf[ks] = *(const bf16x8*)((const char*)Qs + qrow * 128 + g * 16);
        }
    }

    float mrow[4], lsum[4];
    f32x4 oacc[4];
    #pragma unroll
    for (int r = 0; r < 4; ++r) { mrow[r] = -1e30f; lsum[r] = 0.f; }
    #pragma unroll
    for (int fo = 0; fo < 4; ++fo) oacc[fo] = (f32x4){0.f, 0.f, 0.f, 0.f};

    for (int kt = 0; kt < NN / 64; ++kt) {
        __syncthreads();   // previous tile's LDS reads done

        // stage K tile
        #pragma unroll
        for (int rd = 0; rd < 2; ++rd) {
            const int chunk = rd * 4 + wave;
            const int row = chunk * 8 + sr;
            const int gsrc = (sg ^ (row & 7)) * 8;
            gload16(qkv + base + (size_t)(kt * 64 + row) * QKVD + DIM_ + hoff + gsrc,
                    (char*)Ks + chunk * 1024);
        }
        // gather V^T: thread t supplies logical granule (t&7) of V^T row d
        u16x8 vr[2];
        const int vkv0 = (tid & 7) * 8;
        #pragma unroll
        for (int rd = 0; rd < 2; ++rd) {
            const int d = (tid >> 3) + rd * 32;
            const unsigned short* g = qkv + base + (size_t)(kt * 64 + vkv0) * QKVD + 2 * DIM_ + hoff + d;
            #pragma unroll
            for (int j = 0; j < 8; ++j) vr[rd][j] = g[(size_t)j * QKVD];
        }
        if (tid < 64)
            maskf[tid] = (pmask[b * NN + kt * 64 + tid] > 0) ? -__builtin_inff() : 0.f;
        #pragma unroll
        for (int rd = 0; rd < 2; ++rd) {
            const int d = (tid >> 3) + rd * 32;
            const int gw = (tid & 7) ^ (d & 7);
            *(u16x8*)((char*)Vt + d * 128 + gw * 16) = vr[rd];
        }
        __syncthreads();   // staging visible

        // ---- S = Q K^T (acc layout: row=q=(l>>4)*4+r, col=kv=f*16+(l&15)) ----
        f32x4 s[4];
        #pragma unroll
        for (int f = 0; f < 4; ++f) s[f] = (f32x4){0.f, 0.f, 0.f, 0.f};
        #pragma unroll
        for (int ks = 0; ks < 2; ++ks) {
            #pragma unroll
            for (int f = 0; f < 4; ++f) {
                const int krow = f * 16 + (lane & 15);
                const int g = ((lane >> 4) + ks * 4) ^ (lane & 7);
                bf16x8 kf = *(const bf16x8*)((const char*)Ks + krow * 128 + g * 16);
                s[f] = __builtin_amdgcn_mfma_f32_16x16x32_bf16(qf[ks], kf, s[f], 0, 0, 0);
            }
        }

        // ---- online softmax in acc layout ----
        float mc[4];
        #pragma unroll
        for (int f = 0; f < 4; ++f) mc[f] = maskf[f * 16 + (lane & 15)];
        float pw[4][4];   // [f][r]
        float corr[4];
        #pragma unroll
        for (int r = 0; r < 4; ++r) {
            float se[4];
            float mx = mrow[r];
            #pragma unroll
            for (int f = 0; f < 4; ++f) { se[f] = s[f][r] * SCALE + mc[f]; mx = fmaxf(mx, se[f]); }
            #pragma unroll
            for (int off = 1; off < 16; off <<= 1) mx = fmaxf(mx, __shfl_xor(mx, off));
            float ps = 0.f;
            #pragma unroll
            for (int f = 0; f < 4; ++f) { float pv = __expf(se[f] - mx); pw[f][r] = pv; ps += pv; }
            #pragma unroll
            for (int off = 1; off < 16; off <<= 1) ps += __shfl_xor(ps, off);
            corr[r] = __expf(mrow[r] - mx);
            mrow[r] = mx;
            lsum[r] = lsum[r] * corr[r] + ps;
        }
        // write P (bf16) to per-wave LDS [16][72]
        unsigned short* pb = &Ps[wave][0];
        #pragma unroll
        for (int f = 0; f < 4; ++f)
            #pragma unroll
            for (int r = 0; r < 4; ++r)
                pb[((lane >> 4) * 4 + r) * 72 + f * 16 + (lane & 15)] = f2bf(pw[f][r]);
        // rescale O
        #pragma unroll
        for (int fo = 0; fo < 4; ++fo)
            #pragma unroll
            for (int r = 0; r < 4; ++r) oacc[fo][r] *= corr[r];

        // ---- O += P V  (A = P from LDS, B = V^T fragments) ----
        #pragma unroll
        for (int ks = 0; ks < 2; ++ks) {
            bf16x8 pf = *(const bf16x8*)((const char*)pb + ((lane & 15) * 72 + ks * 32 + (lane >> 4) * 8) * 2);
            #pragma unroll
            for (int fo = 0; fo < 4; ++fo) {
                const int g = ((lane >> 4) + ks * 4) ^ (lane & 7);
                bf16x8 vf = *(const bf16x8*)((const char*)Vt + (fo * 16 + (lane & 15)) * 128 + g * 16);
                oacc[fo] = __builtin_amdgcn_mfma_f32_16x16x32_bf16(pf, vf, oacc[fo], 0, 0, 0);
            }
        }
    }

    // ---- epilogue: x[q][h*64+d] = O/l, bf16 ----
    #pragma unroll
    for (int r = 0; r < 4; ++r) {
        const float inv = 1.0f / lsum[r];
        const int q = qt * 64 + wave * 16 + (lane >> 4) * 4 + r;
        #pragma unroll
        for (int fo = 0; fo < 4; ++fo) {
            const int d = fo * 16 + (lane & 15);
            xout[(size_t)(b * NN + q) * DIM_ + hoff + d] = f2bf(oacc[fo][r] * inv);
        }
    }
}

extern "C" void kernel_launch(void* const* d_in, const int* in_sizes, int n_in,
                              void* d_out, int out_size, void* d_ws, size_t ws_size,
                              hipStream_t stream)
{
    const float* x     = (const float*)d_in[0];
    const int*   pmask = (const int*)d_in[1];
    const float* wqkv  = (const float*)d_in[2];
    const float* wfc   = (const float*)d_in[3];
    const float* bfc   = (const float*)d_in[4];
    float* out = (float*)d_out;

    const size_t n_x    = (size_t)MM * DIM_;      // 3.1M
    const size_t n_wqkv = (size_t)QKVD * DIM_;    // 1.77M
    const size_t n_wfc  = (size_t)DIM_ * DIM_;    // 0.59M
    const size_t n_qkv  = (size_t)MM * QKVD;

    unsigned short* xb    = (unsigned short*)d_ws;
    unsigned short* wqkvb = xb + n_x;
    unsigned short* wfcb  = wqkvb + n_wqkv;
    unsigned short* qkvb  = wfcb + n_wfc;
    unsigned short* xattb = qkvb + n_qkv;

    cast_f32_bf16<<<(int)(n_x    / 1024), 256, 0, stream>>>(x,    xb,    (int)n_x);
    cast_f32_bf16<<<(int)(n_wqkv / 1024), 256, 0, stream>>>(wqkv, wqkvb, (int)n_wqkv);
    cast_f32_bf16<<<(int)(n_wfc  / 1024), 256, 0, stream>>>(wfc,  wfcb,  (int)n_wfc);

    gemm_mfma<1><<<dim3(QKVD / 128, MM / 128), 256, 0, stream>>>(xb, wqkvb, nullptr, qkvb, MM, QKVD, DIM_);
    attn_mfma<<<dim3(BB * NH * (NN / 64)), 256, 0, stream>>>(qkvb, pmask, xattb);
    gemm_mfma<0><<<dim3(DIM_ / 128, MM / 128), 256, 0, stream>>>(xattb, wfcb, bfc, out, MM, DIM_, DIM_);
}

// Round 3
// 217.975 us; speedup vs baseline: 4.5793x; 1.0947x over previous
//
#include <hip/hip_runtime.h>
#include <hip/hip_bf16.h>

#define DIM_  768
#define NH    12
#define HD    64
#define BB    2
#define NN    2048
#define MM    (BB*NN)      // 4096
#define QKVD  (3*DIM_)     // 2304

typedef __attribute__((ext_vector_type(8))) short          bf16x8;
typedef __attribute__((ext_vector_type(4))) float          f32x4;

__device__ __forceinline__ unsigned short f2bf(float f) {
    __hip_bfloat16 h = __float2bfloat16(f);
    unsigned short u; __builtin_memcpy(&u, &h, 2); return u;
}

// async global->LDS, 16B/lane. LDS dest = wave-uniform base + lane*16 (HW rule).
__device__ __forceinline__ void gload16(const void* g, void* lds) {
    __builtin_amdgcn_global_load_lds(
        (const __attribute__((address_space(1))) void*)g,
        (__attribute__((address_space(3))) void*)lds, 16, 0, 0);
}

__global__ __launch_bounds__(256)
void cast_f32_bf16(const float* __restrict__ in, unsigned short* __restrict__ out, int n) {
    int i = (blockIdx.x * blockDim.x + threadIdx.x) * 4;
    if (i < n) {
        float4 v = *(const float4*)(in + i);
        ushort4 o; o.x = f2bf(v.x); o.y = f2bf(v.y); o.z = f2bf(v.z); o.w = f2bf(v.w);
        *(ushort4*)(out + i) = o;
    }
}

// ---------------- GEMM1: qkv = x @ w_qkv^T, scattered into per-head q/k/v^T ----
// A:(4096,768) W:(2304,768) bf16. 128x128 tile, 4 waves, BK=32, 2-phase dbuf.
__global__ __launch_bounds__(256)
void gemm_qkv(const unsigned short* __restrict__ A, const unsigned short* __restrict__ W,
              unsigned short* __restrict__ qh, unsigned short* __restrict__ kh,
              unsigned short* __restrict__ vth)
{
    __shared__ unsigned short As[2][128 * 32];
    __shared__ unsigned short Bs[2][128 * 32];
    const int tid = threadIdx.x, lane = tid & 63, wave = tid >> 6;
    const int wr = wave >> 1, wc = wave & 1;
    const int n0 = blockIdx.x * 128, m0 = blockIdx.y * 128;
    const int ldrow = lane >> 2, ldg = lane & 3;

    f32x4 acc[4][4];
    #pragma unroll
    for (int i = 0; i < 4; ++i)
        #pragma unroll
        for (int j = 0; j < 4; ++j) acc[i][j] = (f32x4){0.f, 0.f, 0.f, 0.f};

    #define STAGE_G(buf, k0)                                                         \
        _Pragma("unroll")                                                            \
        for (int rd = 0; rd < 2; ++rd) {                                             \
            const int chunk = rd * 4 + wave;                                         \
            const int row = chunk * 16 + ldrow;                                      \
            gload16(A + (size_t)(m0 + row) * DIM_ + (k0) + ldg * 8,                  \
                    (char*)As[buf] + chunk * 1024);                                  \
            gload16(W + (size_t)(n0 + row) * DIM_ + (k0) + ldg * 8,                  \
                    (char*)Bs[buf] + chunk * 1024);                                  \
        }

    STAGE_G(0, 0);
    __syncthreads();
    int cur = 0;
    for (int kt = 0; kt < DIM_ / 32; ++kt) {
        if (kt < DIM_ / 32 - 1) { STAGE_G(cur ^ 1, (kt + 1) * 32); }
        bf16x8 af[4], bw[4];
        #pragma unroll
        for (int i = 0; i < 4; ++i)
            af[i] = *(const bf16x8*)((const char*)As[cur] + (wr*64 + i*16 + (lane & 15)) * 64 + (lane >> 4) * 16);
        #pragma unroll
        for (int j = 0; j < 4; ++j)
            bw[j] = *(const bf16x8*)((const char*)Bs[cur] + (wc*64 + j*16 + (lane & 15)) * 64 + (lane >> 4) * 16);
        #pragma unroll
        for (int i = 0; i < 4; ++i)
            #pragma unroll
            for (int j = 0; j < 4; ++j)
                acc[i][j] = __builtin_amdgcn_mfma_f32_16x16x32_bf16(af[i], bw[j], acc[i][j], 0, 0, 0);
        __syncthreads();
        cur ^= 1;
    }

    // scatter epilogue: col -> (s, h, d); s=0 -> q[b][h][n][d], s=1 -> k, s=2 -> v^T[b][h][d][n]
    const int r0 = (lane >> 4) * 4, cl = lane & 15;
    #pragma unroll
    for (int j = 0; j < 4; ++j) {
        const int col = n0 + wc * 64 + j * 16 + cl;
        const int s = col / DIM_, rem = col - s * DIM_;
        const int hh = rem >> 6, dd = rem & 63;
        #pragma unroll
        for (int i = 0; i < 4; ++i) {
            const int mb = m0 + wr * 64 + i * 16 + r0;
            const int bq = mb >> 11, nq0 = mb & 2047;
            const size_t hb = (size_t)(bq * NH + hh);
            if (s == 2) {
                ushort4 v;
                v.x = f2bf(acc[i][j][0]); v.y = f2bf(acc[i][j][1]);
                v.z = f2bf(acc[i][j][2]); v.w = f2bf(acc[i][j][3]);
                *(ushort4*)(vth + (hb * 64 + dd) * NN + nq0) = v;
            } else {
                unsigned short* dst = (s == 0 ? qh : kh) + (hb * NN + nq0) * 64 + dd;
                #pragma unroll
                for (int r = 0; r < 4; ++r) dst[(size_t)r * 64] = f2bf(acc[i][j][r]);
            }
        }
    }
    #undef STAGE_G
}

// ---------------- GEMM2: out = xatt @ w_fc^T + b, fp32 out, 2-phase dbuf --------
__global__ __launch_bounds__(256)
void gemm_fc(const unsigned short* __restrict__ A, const unsigned short* __restrict__ W,
             const float* __restrict__ bias, float* __restrict__ C, int Md, int Nd, int K)
{
    __shared__ unsigned short As[2][128 * 32];
    __shared__ unsigned short Bs[2][128 * 32];
    const int tid = threadIdx.x, lane = tid & 63, wave = tid >> 6;
    const int wr = wave >> 1, wc = wave & 1;
    const int n0 = blockIdx.x * 128, m0 = blockIdx.y * 128;
    const int ldrow = lane >> 2, ldg = lane & 3;

    f32x4 acc[4][4];
    #pragma unroll
    for (int i = 0; i < 4; ++i)
        #pragma unroll
        for (int j = 0; j < 4; ++j) acc[i][j] = (f32x4){0.f, 0.f, 0.f, 0.f};

    #define STAGE_G(buf, k0)                                                         \
        _Pragma("unroll")                                                            \
        for (int rd = 0; rd < 2; ++rd) {                                             \
            const int chunk = rd * 4 + wave;                                         \
            const int row = chunk * 16 + ldrow;                                      \
            gload16(A + (size_t)(m0 + row) * K + (k0) + ldg * 8,                     \
                    (char*)As[buf] + chunk * 1024);                                  \
            gload16(W + (size_t)(n0 + row) * K + (k0) + ldg * 8,                     \
                    (char*)Bs[buf] + chunk * 1024);                                  \
        }

    STAGE_G(0, 0);
    __syncthreads();
    int cur = 0;
    const int nk = K / 32;
    for (int kt = 0; kt < nk; ++kt) {
        if (kt < nk - 1) { STAGE_G(cur ^ 1, (kt + 1) * 32); }
        bf16x8 af[4], bw[4];
        #pragma unroll
        for (int i = 0; i < 4; ++i)
            af[i] = *(const bf16x8*)((const char*)As[cur] + (wr*64 + i*16 + (lane & 15)) * 64 + (lane >> 4) * 16);
        #pragma unroll
        for (int j = 0; j < 4; ++j)
            bw[j] = *(const bf16x8*)((const char*)Bs[cur] + (wc*64 + j*16 + (lane & 15)) * 64 + (lane >> 4) * 16);
        #pragma unroll
        for (int i = 0; i < 4; ++i)
            #pragma unroll
            for (int j = 0; j < 4; ++j)
                acc[i][j] = __builtin_amdgcn_mfma_f32_16x16x32_bf16(af[i], bw[j], acc[i][j], 0, 0, 0);
        __syncthreads();
        cur ^= 1;
    }

    const int r0 = (lane >> 4) * 4, cl = lane & 15;
    #pragma unroll
    for (int i = 0; i < 4; ++i)
        #pragma unroll
        for (int j = 0; j < 4; ++j) {
            const int n = n0 + wc * 64 + j * 16 + cl;
            const float bv = bias[n];
            #pragma unroll
            for (int r = 0; r < 4; ++r) {
                const int m = m0 + wr * 64 + i * 16 + r0 + r;
                C[(size_t)m * Nd + n] = acc[i][j][r] + bv;
            }
        }
    #undef STAGE_G
}

// ---------------- Flash attention, per-head layouts, 2-phase K/V dbuf -----------
__global__ __launch_bounds__(256)
void attn_mfma(const unsigned short* __restrict__ qh, const unsigned short* __restrict__ kh,
               const unsigned short* __restrict__ vth, const int* __restrict__ pmask,
               unsigned short* __restrict__ xout)
{
    __shared__ unsigned short Qs[64 * 64];        // 8KB, XOR-granule swizzled
    __shared__ unsigned short Ks[2][64 * 64];     // 16KB
    __shared__ unsigned short Vs[2][64 * 64];     // 16KB (V^T tiles: [d][kv])
    __shared__ unsigned short Ps[4][16 * 72];     // per-wave P
    __shared__ float maskf[2][64];

    const int tid = threadIdx.x, lane = tid & 63, wave = tid >> 6;
    const int ntq = NN / 64;
    const int qt = blockIdx.x % ntq;
    const int bh = blockIdx.x / ntq;
    const int h = bh % NH, b = bh / NH;
    const size_t base = (size_t)(b * NH + h) * NN * 64;   // same for q/k/vt
    constexpr float SCALE = 0.125f;

    const int sr = lane >> 3;   // row within 1KB chunk
    const int sg = lane & 7;    // dest granule; source pre-swizzled

    // stage K/V tile kt into buf: rows stride 64 (K) / 2048 (V^T)
    #define STAGE_KV(buf, kt)                                                          \
        _Pragma("unroll")                                                              \
        for (int rd = 0; rd < 2; ++rd) {                                               \
            const int chunk = rd * 4 + wave;                                           \
            const int row = chunk * 8 + sr;                                            \
            const int gs = (sg ^ (sr & 7)) * 8;                                        \
            gload16(kh + base + (size_t)((kt) * 64 + row) * 64 + gs,                   \
                    (char*)Ks[buf] + chunk * 1024);                                    \
            gload16(vth + base + (size_t)row * NN + (kt) * 64 + gs,                    \
                    (char*)Vs[buf] + chunk * 1024);                                    \
        }

    // ---- prologue: Q + tile 0 + mask 0 ----
    #pragma unroll
    for (int rd = 0; rd < 2; ++rd) {
        const int chunk = rd * 4 + wave;
        const int row = chunk * 8 + sr;
        gload16(qh + base + (size_t)(qt * 64 + row) * 64 + (sg ^ (sr & 7)) * 8,
                (char*)Qs + chunk * 1024);
    }
    STAGE_KV(0, 0);
    if (tid < 64) maskf[0][tid] = (pmask[b * NN + tid] > 0) ? -__builtin_inff() : 0.f;
    __syncthreads();

    bf16x8 qf[2];
    {
        const int qrow = wave * 16 + (lane & 15);
        #pragma unroll
        for (int ks = 0; ks < 2; ++ks) {
            const int g = ((lane >> 4) + ks * 4) ^ (lane & 7);
            qf[ks] = *(const bf16x8*)((const char*)Qs + qrow * 128 + g * 16);
        }
    }

    float mrow[4], lsum[4];
    f32x4 oacc[4];
    #pragma unroll
    for (int r = 0; r < 4; ++r) { mrow[r] = -1e30f; lsum[r] = 0.f; }
    #pragma unroll
    for (int fo = 0; fo < 4; ++fo) oacc[fo] = (f32x4){0.f, 0.f, 0.f, 0.f};

    int cur = 0;
    for (int kt = 0; kt < NN / 64; ++kt) {
        // prefetch next tile into other buffer (lands by next barrier)
        if (kt < NN / 64 - 1) {
            STAGE_KV(cur ^ 1, kt + 1);
            if (tid < 64)
                maskf[cur ^ 1][tid] = (pmask[b * NN + (kt + 1) * 64 + tid] > 0) ? -__builtin_inff() : 0.f;
        }

        // ---- S = Q K^T ----
        f32x4 s[4];
        #pragma unroll
        for (int f = 0; f < 4; ++f) s[f] = (f32x4){0.f, 0.f, 0.f, 0.f};
        #pragma unroll
        for (int ks = 0; ks < 2; ++ks) {
            #pragma unroll
            for (int f = 0; f < 4; ++f) {
                const int krow = f * 16 + (lane & 15);
                const int g = ((lane >> 4) + ks * 4) ^ (lane & 7);
                bf16x8 kf = *(const bf16x8*)((const char*)Ks[cur] + krow * 128 + g * 16);
                s[f] = __builtin_amdgcn_mfma_f32_16x16x32_bf16(qf[ks], kf, s[f], 0, 0, 0);
            }
        }

        // ---- online softmax (acc layout: q=(l>>4)*4+r, kv=f*16+(l&15)) ----
        float mc[4];
        #pragma unroll
        for (int f = 0; f < 4; ++f) mc[f] = maskf[cur][f * 16 + (lane & 15)];
        float pw[4][4], corr[4];
        #pragma unroll
        for (int r = 0; r < 4; ++r) {
            float se[4];
            float mx = mrow[r];
            #pragma unroll
            for (int f = 0; f < 4; ++f) { se[f] = s[f][r] * SCALE + mc[f]; mx = fmaxf(mx, se[f]); }
            #pragma unroll
            for (int off = 1; off < 16; off <<= 1) mx = fmaxf(mx, __shfl_xor(mx, off));
            float ps = 0.f;
            #pragma unroll
            for (int f = 0; f < 4; ++f) { float pv = __expf(se[f] - mx); pw[f][r] = pv; ps += pv; }
            #pragma unroll
            for (int off = 1; off < 16; off <<= 1) ps += __shfl_xor(ps, off);
            corr[r] = __expf(mrow[r] - mx);
            mrow[r] = mx;
            lsum[r] = lsum[r] * corr[r] + ps;
        }
        unsigned short* pb = &Ps[wave][0];
        #pragma unroll
        for (int f = 0; f < 4; ++f)
            #pragma unroll
            for (int r = 0; r < 4; ++r)
                pb[((lane >> 4) * 4 + r) * 72 + f * 16 + (lane & 15)] = f2bf(pw[f][r]);
        #pragma unroll
        for (int fo = 0; fo < 4; ++fo)
            #pragma unroll
            for (int r = 0; r < 4; ++r) oacc[fo][r] *= corr[r];

        // ---- O += P V (A = P from per-wave LDS, B = V^T fragments) ----
        #pragma unroll
        for (int ks = 0; ks < 2; ++ks) {
            bf16x8 pf = *(const bf16x8*)((const char*)pb + ((lane & 15) * 72 + ks * 32 + (lane >> 4) * 8) * 2);
            #pragma unroll
            for (int fo = 0; fo < 4; ++fo) {
                const int g = ((lane >> 4) + ks * 4) ^ (lane & 7);
                bf16x8 vf = *(const bf16x8*)((const char*)Vs[cur] + (fo * 16 + (lane & 15)) * 128 + g * 16);
                oacc[fo] = __builtin_amdgcn_mfma_f32_16x16x32_bf16(pf, vf, oacc[fo], 0, 0, 0);
            }
        }

        __syncthreads();   // drains prefetch vmcnt; all waves done with buf[cur]
        cur ^= 1;
    }

    // ---- epilogue: x[b][n][h*64+d] ----
    #pragma unroll
    for (int r = 0; r < 4; ++r) {
        const float inv = 1.0f / lsum[r];
        const int q = qt * 64 + wave * 16 + (lane >> 4) * 4 + r;
        #pragma unroll
        for (int fo = 0; fo < 4; ++fo) {
            const int d = fo * 16 + (lane & 15);
            xout[(size_t)(b * NN + q) * DIM_ + h * 64 + d] = f2bf(oacc[fo][r] * inv);
        }
    }
    #undef STAGE_KV
}

extern "C" void kernel_launch(void* const* d_in, const int* in_sizes, int n_in,
                              void* d_out, int out_size, void* d_ws, size_t ws_size,
                              hipStream_t stream)
{
    const float* x     = (const float*)d_in[0];
    const int*   pmask = (const int*)d_in[1];
    const float* wqkv  = (const float*)d_in[2];
    const float* wfc   = (const float*)d_in[3];
    const float* bfc   = (const float*)d_in[4];
    float* out = (float*)d_out;

    const size_t n_x    = (size_t)MM * DIM_;
    const size_t n_wqkv = (size_t)QKVD * DIM_;
    const size_t n_wfc  = (size_t)DIM_ * DIM_;
    const size_t n_head = (size_t)BB * NH * NN * 64;   // per q/k/vt buffer

    unsigned short* xb    = (unsigned short*)d_ws;
    unsigned short* wqkvb = xb + n_x;
    unsigned short* wfcb  = wqkvb + n_wqkv;
    unsigned short* qhb   = wfcb + n_wfc;
    unsigned short* khb   = qhb + n_head;
    unsigned short* vthb  = khb + n_head;
    unsigned short* xattb = vthb + n_head;

    cast_f32_bf16<<<(int)(n_x    / 1024), 256, 0, stream>>>(x,    xb,    (int)n_x);
    cast_f32_bf16<<<(int)(n_wqkv / 1024), 256, 0, stream>>>(wqkv, wqkvb, (int)n_wqkv);
    cast_f32_bf16<<<(int)(n_wfc  / 1024), 256, 0, stream>>>(wfc,  wfcb,  (int)n_wfc);

    gemm_qkv<<<dim3(QKVD / 128, MM / 128), 256, 0, stream>>>(xb, wqkvb, qhb, khb, vthb);
    attn_mfma<<<dim3(BB * NH * (NN / 64)), 256, 0, stream>>>(qhb, khb, vthb, pmask, xattb);
    gemm_fc<<<dim3(DIM_ / 128, MM / 128), 256, 0, stream>>>(xattb, wfcb, bfc, out, MM, DIM_, DIM_);
}

// Round 4
// 180.565 us; speedup vs baseline: 5.5281x; 1.2072x over previous
//
#include <hip/hip_runtime.h>
#include <hip/hip_bf16.h>

#define DIM_  768
#define NH    12
#define HD    64
#define BB    2
#define NN    2048
#define MM    (BB*NN)      // 4096
#define QKVD  (3*DIM_)     // 2304

typedef __attribute__((ext_vector_type(8))) short          bf16x8;
typedef __attribute__((ext_vector_type(4))) float          f32x4;

__device__ __forceinline__ unsigned short f2bf(float f) {
    __hip_bfloat16 h = __float2bfloat16(f);
    unsigned short u; __builtin_memcpy(&u, &h, 2); return u;
}

// async global->LDS, 16B/lane. LDS dest = wave-uniform base + lane*16 (HW rule).
__device__ __forceinline__ void gload16(const void* g, void* lds) {
    __builtin_amdgcn_global_load_lds(
        (const __attribute__((address_space(1))) void*)g,
        (__attribute__((address_space(3))) void*)lds, 16, 0, 0);
}

// one fused cast kernel: x, w_qkv, w_fc -> bf16
__global__ __launch_bounds__(256)
void cast_all(const float* __restrict__ x, const float* __restrict__ wqkv,
              const float* __restrict__ wfc, unsigned short* __restrict__ xb,
              unsigned short* __restrict__ wqkvb, unsigned short* __restrict__ wfcb)
{
    const int NV0 = (MM * DIM_) / 4;
    const int NV1 = NV0 + (QKVD * DIM_) / 4;
    const int NV2 = NV1 + (DIM_ * DIM_) / 4;
    int i = blockIdx.x * 256 + threadIdx.x;
    if (i >= NV2) return;
    const float* src; unsigned short* dst;
    if (i < NV0)      { src = x + (size_t)i * 4;            dst = xb + (size_t)i * 4; }
    else if (i < NV1) { size_t j = i - NV0; src = wqkv + j * 4; dst = wqkvb + j * 4; }
    else              { size_t j = i - NV1; src = wfc + j * 4;  dst = wfcb + j * 4; }
    float4 v = *(const float4*)src;
    ushort4 o; o.x = f2bf(v.x); o.y = f2bf(v.y); o.z = f2bf(v.z); o.w = f2bf(v.w);
    *(ushort4*)dst = o;
}

// ---------------- GEMM1: qkv = x @ w_qkv^T -> per-head q (pre-scaled), k, v^T ---
__global__ __launch_bounds__(256)
void gemm_qkv(const unsigned short* __restrict__ A, const unsigned short* __restrict__ W,
              unsigned short* __restrict__ qh, unsigned short* __restrict__ kh,
              unsigned short* __restrict__ vth)
{
    __shared__ unsigned short As[2][128 * 32];
    __shared__ unsigned short Bs[2][128 * 32];
    const int tid = threadIdx.x, lane = tid & 63, wave = tid >> 6;
    const int wr = wave >> 1, wc = wave & 1;
    const int n0 = blockIdx.x * 128, m0 = blockIdx.y * 128;
    const int ldrow = lane >> 2, ldg = lane & 3;
    constexpr float QSCALE = 0.18033688011112042f;   // 64^-0.5 * log2(e)

    f32x4 acc[4][4];
    #pragma unroll
    for (int i = 0; i < 4; ++i)
        #pragma unroll
        for (int j = 0; j < 4; ++j) acc[i][j] = (f32x4){0.f, 0.f, 0.f, 0.f};

    #define STAGE_G(buf, k0)                                                         \
        _Pragma("unroll")                                                            \
        for (int rd = 0; rd < 2; ++rd) {                                             \
            const int chunk = rd * 4 + wave;                                         \
            const int row = chunk * 16 + ldrow;                                      \
            gload16(A + (size_t)(m0 + row) * DIM_ + (k0) + ldg * 8,                  \
                    (char*)As[buf] + chunk * 1024);                                  \
            gload16(W + (size_t)(n0 + row) * DIM_ + (k0) + ldg * 8,                  \
                    (char*)Bs[buf] + chunk * 1024);                                  \
        }

    STAGE_G(0, 0);
    __syncthreads();
    int cur = 0;
    for (int kt = 0; kt < DIM_ / 32; ++kt) {
        if (kt < DIM_ / 32 - 1) { STAGE_G(cur ^ 1, (kt + 1) * 32); }
        bf16x8 af[4], bw[4];
        #pragma unroll
        for (int i = 0; i < 4; ++i)
            af[i] = *(const bf16x8*)((const char*)As[cur] + (wr*64 + i*16 + (lane & 15)) * 64 + (lane >> 4) * 16);
        #pragma unroll
        for (int j = 0; j < 4; ++j)
            bw[j] = *(const bf16x8*)((const char*)Bs[cur] + (wc*64 + j*16 + (lane & 15)) * 64 + (lane >> 4) * 16);
        #pragma unroll
        for (int i = 0; i < 4; ++i)
            #pragma unroll
            for (int j = 0; j < 4; ++j)
                acc[i][j] = __builtin_amdgcn_mfma_f32_16x16x32_bf16(af[i], bw[j], acc[i][j], 0, 0, 0);
        __syncthreads();
        cur ^= 1;
    }

    // scatter: col -> (s,h,d); s=0 -> q (scaled), s=1 -> k, s=2 -> v^T[b][h][d][n]
    const int r0 = (lane >> 4) * 4, cl = lane & 15;
    #pragma unroll
    for (int j = 0; j < 4; ++j) {
        const int col = n0 + wc * 64 + j * 16 + cl;
        const int s = col / DIM_, rem = col - s * DIM_;
        const int hh = rem >> 6, dd = rem & 63;
        #pragma unroll
        for (int i = 0; i < 4; ++i) {
            const int mb = m0 + wr * 64 + i * 16 + r0;
            const int bq = mb >> 11, nq0 = mb & 2047;
            const size_t hb = (size_t)(bq * NH + hh);
            if (s == 2) {
                ushort4 v;
                v.x = f2bf(acc[i][j][0]); v.y = f2bf(acc[i][j][1]);
                v.z = f2bf(acc[i][j][2]); v.w = f2bf(acc[i][j][3]);
                *(ushort4*)(vth + (hb * 64 + dd) * NN + nq0) = v;
            } else {
                const float sc = (s == 0) ? QSCALE : 1.0f;
                unsigned short* dst = (s == 0 ? qh : kh) + (hb * NN + nq0) * 64 + dd;
                #pragma unroll
                for (int r = 0; r < 4; ++r) dst[(size_t)r * 64] = f2bf(acc[i][j][r] * sc);
            }
        }
    }
    #undef STAGE_G
}

// ---------------- GEMM2: out = xatt @ w_fc^T + b (128x64 tile, 384 blocks) ------
__global__ __launch_bounds__(256)
void gemm_fc(const unsigned short* __restrict__ A, const unsigned short* __restrict__ W,
             const float* __restrict__ bias, float* __restrict__ C, int Md, int Nd, int K)
{
    __shared__ unsigned short As[2][128 * 32];
    __shared__ unsigned short Bs[2][64 * 32];
    const int tid = threadIdx.x, lane = tid & 63, wave = tid >> 6;
    const int wr = wave >> 1, wc = wave & 1;
    const int n0 = blockIdx.x * 64, m0 = blockIdx.y * 128;
    const int ldrow = lane >> 2, ldg = lane & 3;

    f32x4 acc[4][2];
    #pragma unroll
    for (int i = 0; i < 4; ++i)
        #pragma unroll
        for (int j = 0; j < 2; ++j) acc[i][j] = (f32x4){0.f, 0.f, 0.f, 0.f};

    #define STAGE_G(buf, k0)                                                         \
        _Pragma("unroll")                                                            \
        for (int rd = 0; rd < 2; ++rd) {                                             \
            const int chunk = rd * 4 + wave;                                         \
            const int row = chunk * 16 + ldrow;                                      \
            gload16(A + (size_t)(m0 + row) * K + (k0) + ldg * 8,                     \
                    (char*)As[buf] + chunk * 1024);                                  \
        }                                                                            \
        gload16(W + (size_t)(n0 + wave * 16 + ldrow) * K + (k0) + ldg * 8,           \
                (char*)Bs[buf] + wave * 1024);

    STAGE_G(0, 0);
    __syncthreads();
    int cur = 0;
    const int nk = K / 32;
    for (int kt = 0; kt < nk; ++kt) {
        if (kt < nk - 1) { STAGE_G(cur ^ 1, (kt + 1) * 32); }
        bf16x8 af[4], bw[2];
        #pragma unroll
        for (int i = 0; i < 4; ++i)
            af[i] = *(const bf16x8*)((const char*)As[cur] + (wr*64 + i*16 + (lane & 15)) * 64 + (lane >> 4) * 16);
        #pragma unroll
        for (int j = 0; j < 2; ++j)
            bw[j] = *(const bf16x8*)((const char*)Bs[cur] + (wc*32 + j*16 + (lane & 15)) * 64 + (lane >> 4) * 16);
        #pragma unroll
        for (int i = 0; i < 4; ++i)
            #pragma unroll
            for (int j = 0; j < 2; ++j)
                acc[i][j] = __builtin_amdgcn_mfma_f32_16x16x32_bf16(af[i], bw[j], acc[i][j], 0, 0, 0);
        __syncthreads();
        cur ^= 1;
    }

    const int r0 = (lane >> 4) * 4, cl = lane & 15;
    #pragma unroll
    for (int i = 0; i < 4; ++i)
        #pragma unroll
        for (int j = 0; j < 2; ++j) {
            const int n = n0 + wc * 32 + j * 16 + cl;
            const float bv = bias[n];
            #pragma unroll
            for (int r = 0; r < 4; ++r) {
                const int m = m0 + wr * 64 + i * 16 + r0 + r;
                C[(size_t)m * Nd + n] = acc[i][j][r] + bv;
            }
        }
    #undef STAGE_G
}

// ---------------- Flash attention: swapped QK^T, lane-local softmax, defer-max ---
__global__ __launch_bounds__(256)
void attn_mfma(const unsigned short* __restrict__ qh, const unsigned short* __restrict__ kh,
               const unsigned short* __restrict__ vth, const int* __restrict__ pmask,
               unsigned short* __restrict__ xout)
{
    __shared__ unsigned short Qs[64 * 64];
    __shared__ unsigned short Ks[2][64 * 64];
    __shared__ unsigned short Vs[2][64 * 64];     // V^T tiles [d][kv]
    __shared__ unsigned short Ps[4][16 * 72];     // per-wave P [q][72]
    __shared__ __align__(16) float maskf[2][64];  // -inf (masked) / 0, log2 domain

    const int tid = threadIdx.x, lane = tid & 63, wave = tid >> 6;
    const int g = lane >> 4, q15 = lane & 15, l7 = lane & 7;
    // XCD-aware swizzle: 768 blocks -> 96-block contiguous chunks per XCD
    const int swz = (blockIdx.x & 7) * 96 + (blockIdx.x >> 3);
    const int qt = swz & 31;
    const int bh = swz >> 5;
    const int h = bh % NH, b = bh / NH;
    const size_t base = (size_t)(b * NH + h) * NN * 64;

    const int sr = lane >> 3, sg = lane & 7;

    #define STAGE_KV(buf, kt)                                                          \
        _Pragma("unroll")                                                              \
        for (int rd = 0; rd < 2; ++rd) {                                               \
            const int chunk = rd * 4 + wave;                                           \
            const int row = chunk * 8 + sr;                                            \
            const int gs = (sg ^ (sr & 7)) * 8;                                        \
            gload16(kh + base + (size_t)((kt) * 64 + row) * 64 + gs,                   \
                    (char*)Ks[buf] + chunk * 1024);                                    \
            gload16(vth + base + (size_t)row * NN + (kt) * 64 + gs,                    \
                    (char*)Vs[buf] + chunk * 1024);                                    \
        }

    // prologue: Q + tile0 + mask0
    #pragma unroll
    for (int rd = 0; rd < 2; ++rd) {
        const int chunk = rd * 4 + wave;
        const int row = chunk * 8 + sr;
        gload16(qh + base + (size_t)(qt * 64 + row) * 64 + (sg ^ (sr & 7)) * 8,
                (char*)Qs + chunk * 1024);
    }
    STAGE_KV(0, 0);
    if (tid < 64) maskf[0][tid] = (pmask[b * NN + tid] > 0) ? -__builtin_inff() : 0.f;
    __syncthreads();

    bf16x8 qf[2];
    {
        const int qrow = wave * 16 + q15;
        #pragma unroll
        for (int ks = 0; ks < 2; ++ks) {
            const int gq = (g + ks * 4) ^ l7;
            qf[ks] = *(const bf16x8*)((const char*)Qs + qrow * 128 + gq * 16);
        }
    }

    float m = -1e30f, lsum = 0.f;
    f32x4 oacc[4];
    #pragma unroll
    for (int fo = 0; fo < 4; ++fo) oacc[fo] = (f32x4){0.f, 0.f, 0.f, 0.f};

    int cur = 0;
    for (int kt = 0; kt < NN / 64; ++kt) {
        if (kt < NN / 64 - 1) {
            STAGE_KV(cur ^ 1, kt + 1);
            if (tid < 64)
                maskf[cur ^ 1][tid] = (pmask[b * NN + (kt + 1) * 64 + tid] > 0) ? -__builtin_inff() : 0.f;
        }

        // ---- S^T = K Q^T + mask (acc: row=kv=f*16+g*4+r, col=q=lane&15) ----
        f32x4 s[4];
        #pragma unroll
        for (int f = 0; f < 4; ++f) s[f] = *(const f32x4*)&maskf[cur][f * 16 + g * 4];
        #pragma unroll
        for (int ks = 0; ks < 2; ++ks) {
            #pragma unroll
            for (int f = 0; f < 4; ++f) {
                const int krow = f * 16 + q15;
                const int gk = (g + ks * 4) ^ l7;
                bf16x8 kf = *(const bf16x8*)((const char*)Ks[cur] + krow * 128 + gk * 16);
                s[f] = __builtin_amdgcn_mfma_f32_16x16x32_bf16(kf, qf[ks], s[f], 0, 0, 0);
            }
        }

        // ---- lane-local online softmax (log2 domain), defer-max ----
        float pmax = -1e30f;
        #pragma unroll
        for (int f = 0; f < 4; ++f)
            pmax = fmaxf(pmax, fmaxf(fmaxf(s[f][0], s[f][1]), fmaxf(s[f][2], s[f][3])));
        pmax = fmaxf(pmax, __shfl_xor(pmax, 16));
        pmax = fmaxf(pmax, __shfl_xor(pmax, 32));
        if (__any(pmax > m + 10.0f)) {
            const float mnew = fmaxf(m, pmax);
            const float corr = __builtin_amdgcn_exp2f(m - mnew);
            m = mnew;
            lsum *= corr;
            float c[4];
            #pragma unroll
            for (int r = 0; r < 4; ++r) c[r] = __shfl(corr, g * 4 + r);
            #pragma unroll
            for (int fo = 0; fo < 4; ++fo)
                #pragma unroll
                for (int r = 0; r < 4; ++r) oacc[fo][r] *= c[r];
        }
        float pw[4][4], ps = 0.f;
        #pragma unroll
        for (int f = 0; f < 4; ++f)
            #pragma unroll
            for (int r = 0; r < 4; ++r) {
                const float p = __builtin_amdgcn_exp2f(s[f][r] - m);
                pw[f][r] = p; ps += p;
            }
        ps += __shfl_xor(ps, 16);
        ps += __shfl_xor(ps, 32);
        lsum += ps;

        // P -> LDS: lane owns column q, rows f*16+g*4..+3 -> packed b64 per f
        unsigned short* pb = &Ps[wave][0];
        #pragma unroll
        for (int f = 0; f < 4; ++f) {
            ushort4 u;
            u.x = f2bf(pw[f][0]); u.y = f2bf(pw[f][1]);
            u.z = f2bf(pw[f][2]); u.w = f2bf(pw[f][3]);
            *(ushort4*)(pb + q15 * 72 + f * 16 + g * 4) = u;
        }

        // ---- O += P V (A = P from per-wave LDS, B = V^T fragments) ----
        #pragma unroll
        for (int ks = 0; ks < 2; ++ks) {
            bf16x8 pf = *(const bf16x8*)((const char*)pb + (q15 * 72 + ks * 32 + g * 8) * 2);
            #pragma unroll
            for (int fo = 0; fo < 4; ++fo) {
                const int gv = (g + ks * 4) ^ l7;
                bf16x8 vf = *(const bf16x8*)((const char*)Vs[cur] + (fo * 16 + q15) * 128 + gv * 16);
                oacc[fo] = __builtin_amdgcn_mfma_f32_16x16x32_bf16(pf, vf, oacc[fo], 0, 0, 0);
            }
        }

        __syncthreads();
        cur ^= 1;
    }

    // epilogue: redistribute lsum (row q' = g*4+r held by lane q')
    float linv[4];
    #pragma unroll
    for (int r = 0; r < 4; ++r) linv[r] = 1.0f / __shfl(lsum, g * 4 + r);
    #pragma unroll
    for (int r = 0; r < 4; ++r) {
        const int q = qt * 64 + wave * 16 + g * 4 + r;
        #pragma unroll
        for (int fo = 0; fo < 4; ++fo) {
            const int d = fo * 16 + q15;
            xout[(size_t)(b * NN + q) * DIM_ + h * 64 + d] = f2bf(oacc[fo][r] * linv[r]);
        }
    }
    #undef STAGE_KV
}

extern "C" void kernel_launch(void* const* d_in, const int* in_sizes, int n_in,
                              void* d_out, int out_size, void* d_ws, size_t ws_size,
                              hipStream_t stream)
{
    const float* x     = (const float*)d_in[0];
    const int*   pmask = (const int*)d_in[1];
    const float* wqkv  = (const float*)d_in[2];
    const float* wfc   = (const float*)d_in[3];
    const float* bfc   = (const float*)d_in[4];
    float* out = (float*)d_out;

    const size_t n_x    = (size_t)MM * DIM_;
    const size_t n_wqkv = (size_t)QKVD * DIM_;
    const size_t n_wfc  = (size_t)DIM_ * DIM_;
    const size_t n_head = (size_t)BB * NH * NN * 64;

    unsigned short* xb    = (unsigned short*)d_ws;
    unsigned short* wqkvb = xb + n_x;
    unsigned short* wfcb  = wqkvb + n_wqkv;
    unsigned short* qhb   = wfcb + n_wfc;
    unsigned short* khb   = qhb + n_head;
    unsigned short* vthb  = khb + n_head;
    unsigned short* xattb = vthb + n_head;

    const int nv = (int)((n_x + n_wqkv + n_wfc) / 4);
    cast_all<<<(nv + 255) / 256, 256, 0, stream>>>(x, wqkv, wfc, xb, wqkvb, wfcb);

    gemm_qkv<<<dim3(QKVD / 128, MM / 128), 256, 0, stream>>>(xb, wqkvb, qhb, khb, vthb);
    attn_mfma<<<dim3(BB * NH * (NN / 64)), 256, 0, stream>>>(qhb, khb, vthb, pmask, xattb);
    gemm_fc<<<dim3(DIM_ / 64, MM / 128), 256, 0, stream>>>(xattb, wfcb, bfc, out, MM, DIM_, DIM_);
}

// Round 5
// 179.820 us; speedup vs baseline: 5.5510x; 1.0041x over previous
//
#include <hip/hip_runtime.h>
#include <hip/hip_bf16.h>

#define DIM_  768
#define NH    12
#define HD    64
#define BB    2
#define NN    2048
#define MM    (BB*NN)      // 4096
#define QKVD  (3*DIM_)     // 2304

typedef __attribute__((ext_vector_type(8))) short          bf16x8;
typedef __attribute__((ext_vector_type(4))) float          f32x4;

__device__ __forceinline__ unsigned short f2bf(float f) {
    __hip_bfloat16 h = __float2bfloat16(f);
    unsigned short u; __builtin_memcpy(&u, &h, 2); return u;
}

// async global->LDS, 16B/lane. LDS dest = wave-uniform base + lane*16 (HW rule).
__device__ __forceinline__ void gload16(const void* g, void* lds) {
    __builtin_amdgcn_global_load_lds(
        (const __attribute__((address_space(1))) void*)g,
        (__attribute__((address_space(3))) void*)lds, 16, 0, 0);
}

// one fused cast kernel: x, w_qkv, w_fc -> bf16
__global__ __launch_bounds__(256)
void cast_all(const float* __restrict__ x, const float* __restrict__ wqkv,
              const float* __restrict__ wfc, unsigned short* __restrict__ xb,
              unsigned short* __restrict__ wqkvb, unsigned short* __restrict__ wfcb)
{
    const int NV0 = (MM * DIM_) / 4;
    const int NV1 = NV0 + (QKVD * DIM_) / 4;
    const int NV2 = NV1 + (DIM_ * DIM_) / 4;
    int i = blockIdx.x * 256 + threadIdx.x;
    if (i >= NV2) return;
    const float* src; unsigned short* dst;
    if (i < NV0)      { src = x + (size_t)i * 4;            dst = xb + (size_t)i * 4; }
    else if (i < NV1) { size_t j = i - NV0; src = wqkv + j * 4; dst = wqkvb + j * 4; }
    else              { size_t j = i - NV1; src = wfc + j * 4;  dst = wfcb + j * 4; }
    float4 v = *(const float4*)src;
    ushort4 o; o.x = f2bf(v.x); o.y = f2bf(v.y); o.z = f2bf(v.z); o.w = f2bf(v.w);
    *(ushort4*)dst = o;
}

// ---------------- GEMM1: qkv = x @ w_qkv^T -> per-head q (pre-scaled), k, v^T ---
__global__ __launch_bounds__(256)
void gemm_qkv(const unsigned short* __restrict__ A, const unsigned short* __restrict__ W,
              unsigned short* __restrict__ qh, unsigned short* __restrict__ kh,
              unsigned short* __restrict__ vth)
{
    __shared__ unsigned short As[2][128 * 32];
    __shared__ unsigned short Bs[2][128 * 32];
    const int tid = threadIdx.x, lane = tid & 63, wave = tid >> 6;
    const int wr = wave >> 1, wc = wave & 1;
    const int n0 = blockIdx.x * 128, m0 = blockIdx.y * 128;
    const int ldrow = lane >> 2, ldg = lane & 3;
    constexpr float QSCALE = 0.18033688011112042f;   // 64^-0.5 * log2(e)

    f32x4 acc[4][4];
    #pragma unroll
    for (int i = 0; i < 4; ++i)
        #pragma unroll
        for (int j = 0; j < 4; ++j) acc[i][j] = (f32x4){0.f, 0.f, 0.f, 0.f};

    #define STAGE_G(buf, k0)                                                         \
        _Pragma("unroll")                                                            \
        for (int rd = 0; rd < 2; ++rd) {                                             \
            const int chunk = rd * 4 + wave;                                         \
            const int row = chunk * 16 + ldrow;                                      \
            gload16(A + (size_t)(m0 + row) * DIM_ + (k0) + ldg * 8,                  \
                    (char*)As[buf] + chunk * 1024);                                  \
            gload16(W + (size_t)(n0 + row) * DIM_ + (k0) + ldg * 8,                  \
                    (char*)Bs[buf] + chunk * 1024);                                  \
        }

    STAGE_G(0, 0);
    __syncthreads();
    int cur = 0;
    for (int kt = 0; kt < DIM_ / 32; ++kt) {
        if (kt < DIM_ / 32 - 1) { STAGE_G(cur ^ 1, (kt + 1) * 32); }
        bf16x8 af[4], bw[4];
        #pragma unroll
        for (int i = 0; i < 4; ++i)
            af[i] = *(const bf16x8*)((const char*)As[cur] + (wr*64 + i*16 + (lane & 15)) * 64 + (lane >> 4) * 16);
        #pragma unroll
        for (int j = 0; j < 4; ++j)
            bw[j] = *(const bf16x8*)((const char*)Bs[cur] + (wc*64 + j*16 + (lane & 15)) * 64 + (lane >> 4) * 16);
        #pragma unroll
        for (int i = 0; i < 4; ++i)
            #pragma unroll
            for (int j = 0; j < 4; ++j)
                acc[i][j] = __builtin_amdgcn_mfma_f32_16x16x32_bf16(af[i], bw[j], acc[i][j], 0, 0, 0);
        __syncthreads();
        cur ^= 1;
    }

    // scatter epilogue; s = col/768 is BLOCK-UNIFORM (768 % 128 == 0)
    const int r0 = (lane >> 4) * 4, cl = lane & 15;
    const int s = n0 / DIM_;
    const int rem0 = n0 - s * DIM_ + wc * 64;
    if (s == 2) {
        #pragma unroll
        for (int j = 0; j < 4; ++j) {
            const int rem = rem0 + j * 16 + cl;
            const int hh = rem >> 6, dd = rem & 63;
            #pragma unroll
            for (int i = 0; i < 4; ++i) {
                const int mb = m0 + wr * 64 + i * 16 + r0;
                const int bq = mb >> 11, nq0 = mb & 2047;
                const size_t hb = (size_t)(bq * NH + hh);
                ushort4 v;
                v.x = f2bf(acc[i][j][0]); v.y = f2bf(acc[i][j][1]);
                v.z = f2bf(acc[i][j][2]); v.w = f2bf(acc[i][j][3]);
                *(ushort4*)(vth + (hb * 64 + dd) * NN + nq0) = v;
            }
        }
    } else {
        unsigned short* const dstb = (s == 0) ? qh : kh;
        const float sc = (s == 0) ? QSCALE : 1.0f;
        #pragma unroll
        for (int j = 0; j < 4; ++j) {
            const int rem = rem0 + j * 16 + cl;
            const int hh = rem >> 6, dd = rem & 63;
            #pragma unroll
            for (int i = 0; i < 4; ++i) {
                const int mb = m0 + wr * 64 + i * 16 + r0;
                const int bq = mb >> 11, nq0 = mb & 2047;
                const size_t hb = (size_t)(bq * NH + hh);
                unsigned short* dst = dstb + (hb * NN + nq0) * 64 + dd;
                #pragma unroll
                for (int r = 0; r < 4; ++r) dst[(size_t)r * 64] = f2bf(acc[i][j][r] * sc);
            }
        }
    }
    #undef STAGE_G
}

// ---------------- GEMM2: out = xatt @ w_fc^T + b (128x64 tile, 384 blocks) ------
__global__ __launch_bounds__(256)
void gemm_fc(const unsigned short* __restrict__ A, const unsigned short* __restrict__ W,
             const float* __restrict__ bias, float* __restrict__ C, int Md, int Nd, int K)
{
    __shared__ unsigned short As[2][128 * 32];
    __shared__ unsigned short Bs[2][64 * 32];
    const int tid = threadIdx.x, lane = tid & 63, wave = tid >> 6;
    const int wr = wave >> 1, wc = wave & 1;
    const int n0 = blockIdx.x * 64, m0 = blockIdx.y * 128;
    const int ldrow = lane >> 2, ldg = lane & 3;

    f32x4 acc[4][2];
    #pragma unroll
    for (int i = 0; i < 4; ++i)
        #pragma unroll
        for (int j = 0; j < 2; ++j) acc[i][j] = (f32x4){0.f, 0.f, 0.f, 0.f};

    #define STAGE_G(buf, k0)                                                         \
        _Pragma("unroll")                                                            \
        for (int rd = 0; rd < 2; ++rd) {                                             \
            const int chunk = rd * 4 + wave;                                         \
            const int row = chunk * 16 + ldrow;                                      \
            gload16(A + (size_t)(m0 + row) * K + (k0) + ldg * 8,                     \
                    (char*)As[buf] + chunk * 1024);                                  \
        }                                                                            \
        gload16(W + (size_t)(n0 + wave * 16 + ldrow) * K + (k0) + ldg * 8,           \
                (char*)Bs[buf] + wave * 1024);

    STAGE_G(0, 0);
    __syncthreads();
    int cur = 0;
    const int nk = K / 32;
    for (int kt = 0; kt < nk; ++kt) {
        if (kt < nk - 1) { STAGE_G(cur ^ 1, (kt + 1) * 32); }
        bf16x8 af[4], bw[2];
        #pragma unroll
        for (int i = 0; i < 4; ++i)
            af[i] = *(const bf16x8*)((const char*)As[cur] + (wr*64 + i*16 + (lane & 15)) * 64 + (lane >> 4) * 16);
        #pragma unroll
        for (int j = 0; j < 2; ++j)
            bw[j] = *(const bf16x8*)((const char*)Bs[cur] + (wc*32 + j*16 + (lane & 15)) * 64 + (lane >> 4) * 16);
        #pragma unroll
        for (int i = 0; i < 4; ++i)
            #pragma unroll
            for (int j = 0; j < 2; ++j)
                acc[i][j] = __builtin_amdgcn_mfma_f32_16x16x32_bf16(af[i], bw[j], acc[i][j], 0, 0, 0);
        __syncthreads();
        cur ^= 1;
    }

    const int r0 = (lane >> 4) * 4, cl = lane & 15;
    #pragma unroll
    for (int i = 0; i < 4; ++i)
        #pragma unroll
        for (int j = 0; j < 2; ++j) {
            const int n = n0 + wc * 32 + j * 16 + cl;
            const float bv = bias[n];
            #pragma unroll
            for (int r = 0; r < 4; ++r) {
                const int m = m0 + wr * 64 + i * 16 + r0 + r;
                C[(size_t)m * Nd + n] = acc[i][j][r] + bv;
            }
        }
    #undef STAGE_G
}

// ---------------- Flash attention: swapped QK^T, lane-local softmax, defer-max ---
__global__ __launch_bounds__(256)
void attn_mfma(const unsigned short* __restrict__ qh, const unsigned short* __restrict__ kh,
               const unsigned short* __restrict__ vth, const int* __restrict__ pmask,
               unsigned short* __restrict__ xout)
{
    __shared__ unsigned short Qs[64 * 64];
    __shared__ unsigned short Ks[2][64 * 64];
    __shared__ unsigned short Vs[2][64 * 64];     // V^T tiles [d][kv]
    __shared__ unsigned short Ps[4][16 * 72];     // per-wave P [q][72]
    __shared__ __align__(16) float maskf[2][64];  // -inf (masked) / 0, log2 domain

    const int tid = threadIdx.x, lane = tid & 63, wave = tid >> 6;
    const int g = lane >> 4, q15 = lane & 15, l7 = lane & 7;
    // XCD-aware swizzle: 768 blocks -> 96-block contiguous chunks per XCD
    const int swz = (blockIdx.x & 7) * 96 + (blockIdx.x >> 3);
    const int qt = swz & 31;
    const int bh = swz >> 5;
    const int h = bh % NH, b = bh / NH;
    const size_t base = (size_t)(b * NH + h) * NN * 64;

    const int sr = lane >> 3, sg = lane & 7;

    #define STAGE_KV(buf, kt)                                                          \
        _Pragma("unroll")                                                              \
        for (int rd = 0; rd < 2; ++rd) {                                               \
            const int chunk = rd * 4 + wave;                                           \
            const int row = chunk * 8 + sr;                                            \
            const int gs = (sg ^ (sr & 7)) * 8;                                        \
            gload16(kh + base + (size_t)((kt) * 64 + row) * 64 + gs,                   \
                    (char*)Ks[buf] + chunk * 1024);                                    \
            gload16(vth + base + (size_t)row * NN + (kt) * 64 + gs,                    \
                    (char*)Vs[buf] + chunk * 1024);                                    \
        }

    // prologue: Q + tile0 + mask0
    #pragma unroll
    for (int rd = 0; rd < 2; ++rd) {
        const int chunk = rd * 4 + wave;
        const int row = chunk * 8 + sr;
        gload16(qh + base + (size_t)(qt * 64 + row) * 64 + (sg ^ (sr & 7)) * 8,
                (char*)Qs + chunk * 1024);
    }
    STAGE_KV(0, 0);
    if (tid < 64) maskf[0][tid] = (pmask[b * NN + tid] > 0) ? -__builtin_inff() : 0.f;
    __syncthreads();

    bf16x8 qf[2];
    {
        const int qrow = wave * 16 + q15;
        #pragma unroll
        for (int ks = 0; ks < 2; ++ks) {
            const int gq = (g + ks * 4) ^ l7;
            qf[ks] = *(const bf16x8*)((const char*)Qs + qrow * 128 + gq * 16);
        }
    }

    float m = -1e30f, lsum = 0.f;
    f32x4 oacc[4];
    #pragma unroll
    for (int fo = 0; fo < 4; ++fo) oacc[fo] = (f32x4){0.f, 0.f, 0.f, 0.f};

    int cur = 0;
    for (int kt = 0; kt < NN / 64; ++kt) {
        if (kt < NN / 64 - 1) {
            STAGE_KV(cur ^ 1, kt + 1);
            if (tid < 64)
                maskf[cur ^ 1][tid] = (pmask[b * NN + (kt + 1) * 64 + tid] > 0) ? -__builtin_inff() : 0.f;
        }

        // ---- S^T = K Q^T + mask (acc: row=kv=f*16+g*4+r, col=q=lane&15) ----
        f32x4 s[4];
        #pragma unroll
        for (int f = 0; f < 4; ++f) s[f] = *(const f32x4*)&maskf[cur][f * 16 + g * 4];
        __builtin_amdgcn_s_setprio(1);
        #pragma unroll
        for (int ks = 0; ks < 2; ++ks) {
            #pragma unroll
            for (int f = 0; f < 4; ++f) {
                const int krow = f * 16 + q15;
                const int gk = (g + ks * 4) ^ l7;
                bf16x8 kf = *(const bf16x8*)((const char*)Ks[cur] + krow * 128 + gk * 16);
                s[f] = __builtin_amdgcn_mfma_f32_16x16x32_bf16(kf, qf[ks], s[f], 0, 0, 0);
            }
        }
        __builtin_amdgcn_s_setprio(0);

        // ---- lane-local online softmax (log2 domain), defer-max ----
        float pmax;
        {
            const float a0 = fmaxf(fmaxf(s[0][0], s[0][1]), fmaxf(s[0][2], s[0][3]));
            const float a1 = fmaxf(fmaxf(s[1][0], s[1][1]), fmaxf(s[1][2], s[1][3]));
            const float a2 = fmaxf(fmaxf(s[2][0], s[2][1]), fmaxf(s[2][2], s[2][3]));
            const float a3 = fmaxf(fmaxf(s[3][0], s[3][1]), fmaxf(s[3][2], s[3][3]));
            pmax = fmaxf(fmaxf(a0, a1), fmaxf(a2, a3));
        }
        pmax = fmaxf(pmax, __shfl_xor(pmax, 16));
        pmax = fmaxf(pmax, __shfl_xor(pmax, 32));
        if (__any(pmax > m + 10.0f)) {
            const float mnew = fmaxf(m, pmax);
            const float corr = __builtin_amdgcn_exp2f(m - mnew);
            m = mnew;
            lsum *= corr;
            float c[4];
            #pragma unroll
            for (int r = 0; r < 4; ++r) c[r] = __shfl(corr, g * 4 + r);
            #pragma unroll
            for (int fo = 0; fo < 4; ++fo)
                #pragma unroll
                for (int r = 0; r < 4; ++r) oacc[fo][r] *= c[r];
        }
        float pw[4][4], ps = 0.f;
        #pragma unroll
        for (int f = 0; f < 4; ++f)
            #pragma unroll
            for (int r = 0; r < 4; ++r) {
                const float p = __builtin_amdgcn_exp2f(s[f][r] - m);
                pw[f][r] = p; ps += p;
            }
        ps += __shfl_xor(ps, 16);
        ps += __shfl_xor(ps, 32);
        lsum += ps;

        // P -> LDS: lane owns column q, rows f*16+g*4..+3 -> packed b64 per f
        unsigned short* pb = &Ps[wave][0];
        #pragma unroll
        for (int f = 0; f < 4; ++f) {
            ushort4 u;
            u.x = f2bf(pw[f][0]); u.y = f2bf(pw[f][1]);
            u.z = f2bf(pw[f][2]); u.w = f2bf(pw[f][3]);
            *(ushort4*)(pb + q15 * 72 + f * 16 + g * 4) = u;
        }

        // ---- O += P V (A = P from per-wave LDS, B = V^T fragments) ----
        __builtin_amdgcn_s_setprio(1);
        #pragma unroll
        for (int ks = 0; ks < 2; ++ks) {
            bf16x8 pf = *(const bf16x8*)((const char*)pb + (q15 * 72 + ks * 32 + g * 8) * 2);
            #pragma unroll
            for (int fo = 0; fo < 4; ++fo) {
                const int gv = (g + ks * 4) ^ l7;
                bf16x8 vf = *(const bf16x8*)((const char*)Vs[cur] + (fo * 16 + q15) * 128 + gv * 16);
                oacc[fo] = __builtin_amdgcn_mfma_f32_16x16x32_bf16(pf, vf, oacc[fo], 0, 0, 0);
            }
        }
        __builtin_amdgcn_s_setprio(0);

        __syncthreads();
        cur ^= 1;
    }

    // epilogue: redistribute lsum (row q' = g*4+r held by lane q')
    float linv[4];
    #pragma unroll
    for (int r = 0; r < 4; ++r) linv[r] = 1.0f / __shfl(lsum, g * 4 + r);
    #pragma unroll
    for (int r = 0; r < 4; ++r) {
        const int q = qt * 64 + wave * 16 + g * 4 + r;
        #pragma unroll
        for (int fo = 0; fo < 4; ++fo) {
            const int d = fo * 16 + q15;
            xout[(size_t)(b * NN + q) * DIM_ + h * 64 + d] = f2bf(oacc[fo][r] * linv[r]);
        }
    }
    #undef STAGE_KV
}

extern "C" void kernel_launch(void* const* d_in, const int* in_sizes, int n_in,
                              void* d_out, int out_size, void* d_ws, size_t ws_size,
                              hipStream_t stream)
{
    const float* x     = (const float*)d_in[0];
    const int*   pmask = (const int*)d_in[1];
    const float* wqkv  = (const float*)d_in[2];
    const float* wfc   = (const float*)d_in[3];
    const float* bfc   = (const float*)d_in[4];
    float* out = (float*)d_out;

    const size_t n_x    = (size_t)MM * DIM_;
    const size_t n_wqkv = (size_t)QKVD * DIM_;
    const size_t n_wfc  = (size_t)DIM_ * DIM_;
    const size_t n_head = (size_t)BB * NH * NN * 64;

    unsigned short* xb    = (unsigned short*)d_ws;
    unsigned short* wqkvb = xb + n_x;
    unsigned short* wfcb  = wqkvb + n_wqkv;
    unsigned short* qhb   = wfcb + n_wfc;
    unsigned short* khb   = qhb + n_head;
    unsigned short* vthb  = khb + n_head;
    unsigned short* xattb = vthb + n_head;

    const int nv = (int)((n_x + n_wqkv + n_wfc) / 4);
    cast_all<<<(nv + 255) / 256, 256, 0, stream>>>(x, wqkv, wfc, xb, wqkvb, wfcb);

    gemm_qkv<<<dim3(QKVD / 128, MM / 128), 256, 0, stream>>>(xb, wqkvb, qhb, khb, vthb);
    attn_mfma<<<dim3(BB * NH * (NN / 64)), 256, 0, stream>>>(qhb, khb, vthb, pmask, xattb);
    gemm_fc<<<dim3(DIM_ / 64, MM / 128), 256, 0, stream>>>(xattb, wfcb, bfc, out, MM, DIM_, DIM_);
}